// Round 2
// baseline (12575.272 us; speedup 1.0000x reference)
//
#include <hip/hip_runtime.h>

typedef _Float16 f16x8  __attribute__((ext_vector_type(8)));
typedef float    f32x16 __attribute__((ext_vector_type(16)));

#define TSTEPS 500
#define NB 512
#define LOG2E 1.442695041f

// f64 exp, Cody-Waite reduction + degree-11 Taylor, rel err ~1e-15.
__device__ __forceinline__ double exp_d(double v){
  v = fmin(fmax(v, -700.0), 700.0);
  double t = v * 1.4426950408889634;           // v / ln2
  double n = rint(t);
  double f = fma(-n, 6.931471803691238e-01, v);   // LN2_HI
  f = fma(-n, 1.9082149292705877e-10, f);         // LN2_LO
  double p = 2.5052108385441718e-08;           // 1/11!
  p = fma(p, f, 2.7557319223985893e-07);       // 1/10!
  p = fma(p, f, 2.7557319223985888e-06);       // 1/9!
  p = fma(p, f, 2.4801587301587302e-05);       // 1/8!
  p = fma(p, f, 1.9841269841269841e-04);       // 1/7!
  p = fma(p, f, 1.3888888888888889e-03);       // 1/6!
  p = fma(p, f, 8.3333333333333332e-03);       // 1/5!
  p = fma(p, f, 4.1666666666666664e-02);       // 1/4!
  p = fma(p, f, 1.6666666666666666e-01);       // 1/3!
  p = fma(p, f, 0.5);
  p = fma(p, f, 1.0);
  p = fma(p, f, 1.0);
  long long bits = (1023LL + (long long)n) << 52;
  return p * __longlong_as_double(bits);
}

// ---------------------------------------------------------------------------
// Fused GRU, 256 threads (4 waves) per (g,n) sequence.
// Column-split: thread (j=tid>>2, q=tid&3) owns rows {j,64+j,128+j} of W_ih
// and W_hh over cols [16q,16q+16) -> 96 weight VGPRs, only 16 ds_read_b128
// per step (4x fewer than row-per-thread). Quad shfl_xor reduces the 4
// column-partials; gates computed by ALL lanes in parallel (redundant over
// q, bitwise identical) -> no preh/prex exchange, no wave0-only phase.
// Ping-pong h/x LDS buffers -> ONE barrier per step. LDS index c+2*(c>>4)
// (group stride 18 doubles, 16B aligned) makes the 4 q-group addresses per
// ds_read land on disjoint banks. x staged as f64 by wave0, prefetched 2
// steps ahead. f64 gate math identical to the passing kernel; one-shot f16
// rounding outside the recurrence.
// ---------------------------------------------------------------------------
__global__ __launch_bounds__(256, 3) void gru_f64(
    const float* __restrict__ x,    // [500,512,64] f32
    const float* __restrict__ st,   // [3,512,64] f32
    const float* __restrict__ wih0, const float* __restrict__ whh0,
    const float* __restrict__ bih0, const float* __restrict__ bhh0,
    const float* __restrict__ wih1, const float* __restrict__ whh1,
    const float* __restrict__ bih1, const float* __restrict__ bhh1,
    const float* __restrict__ wih2, const float* __restrict__ whh2,
    const float* __restrict__ bih2, const float* __restrict__ bhh2,
    _Float16* __restrict__ qkv,      // ws: [3,500,512,64] f16
    float* __restrict__ out_state)   // [3,512,64] f32
{
  __shared__ __align__(16) double hsh[2][72];
  __shared__ __align__(16) double xsh[2][72];

  const int tid = threadIdx.x;
  const int j = tid >> 2;            // h-index 0..63
  const int q = tid & 3;             // column quarter
  const int g = blockIdx.x >> 9;
  const int n = blockIdx.x & 511;

  const float* wih = (g==0) ? wih0 : ((g==1) ? wih1 : wih2);
  const float* whh = (g==0) ? whh0 : ((g==1) ? whh1 : whh2);
  const float* bih = (g==0) ? bih0 : ((g==1) ? bih1 : bih2);
  const float* bhh = (g==0) ? bhh0 : ((g==1) ? bhh1 : bhh2);

  // 96 VGPRs of f32 weights: rows j(r), 64+j(z), 128+j(n); cols [16q,16q+16)
  // Lane tid reads floats [16*tid .. 16*tid+15] -> perfectly coalesced.
  float4 wiR[4], wiZ[4], wiN[4], whR[4], whZ[4], whN[4];
  {
    const float4* pR = (const float4*)(wih + (size_t)(       j)*64 + q*16);
    const float4* pZ = (const float4*)(wih + (size_t)( 64 + j)*64 + q*16);
    const float4* pN = (const float4*)(wih + (size_t)(128 + j)*64 + q*16);
    const float4* rR = (const float4*)(whh + (size_t)(       j)*64 + q*16);
    const float4* rZ = (const float4*)(whh + (size_t)( 64 + j)*64 + q*16);
    const float4* rN = (const float4*)(whh + (size_t)(128 + j)*64 + q*16);
    #pragma unroll
    for (int k=0;k<4;++k){
      wiR[k]=pR[k]; wiZ[k]=pZ[k]; wiN[k]=pN[k];
      whR[k]=rR[k]; whZ[k]=rZ[k]; whN[k]=rN[k];
    }
  }
  const double bR  = (double)bih[j]      + (double)bhh[j];      // r: bi+bh fold
  const double bZ  = (double)bih[64+j]   + (double)bhh[64+j];   // z: bi+bh fold
  const double biN = (double)bih[128+j];
  const double bhN = (double)bhh[128+j];

  double h = (double)st[(size_t)(g*512 + n)*64 + j];   // redundant across q

  const float* xp = x + (size_t)n*64 + tid;            // loader lanes tid<64
  float xc0 = 0.f, xc1 = 0.f;
  if (tid < 64){
    int ci = tid + 2*(tid>>4);
    hsh[0][ci] = (double)st[(size_t)(g*512 + n)*64 + tid];
    xsh[0][ci] = (double)xp[0];
    xc0 = xp[(size_t)NB*64];
    xc1 = xp[(size_t)2*NB*64];
  }
  _Float16* qout = qkv + ((size_t)g*TSTEPS*NB + n)*64 + j;
  __syncthreads();

  for (int t=0; t<TSTEPS; ++t){
    const int cur = t & 1, nxt = cur ^ 1;
    const double2* hp = (const double2*)(&hsh[cur][18*q]);  // 144B-aligned
    const double2* xq = (const double2*)(&xsh[cur][18*q]);

    double hdR=0.0, hdZ=0.0, hdN=0.0, xdR=0.0, xdZ=0.0, xdN=0.0;
    #pragma unroll
    for (int w=0; w<4; ++w){
      double2 h01 = hp[2*w], h23 = hp[2*w+1];
      double2 x01 = xq[2*w], x23 = xq[2*w+1];
      float4 ar = whR[w], az = whZ[w], an = whN[w];
      float4 br = wiR[w], bz = wiZ[w], bn = wiN[w];
      hdR = fma((double)ar.x, h01.x, hdR); hdR = fma((double)ar.y, h01.y, hdR);
      hdR = fma((double)ar.z, h23.x, hdR); hdR = fma((double)ar.w, h23.y, hdR);
      hdZ = fma((double)az.x, h01.x, hdZ); hdZ = fma((double)az.y, h01.y, hdZ);
      hdZ = fma((double)az.z, h23.x, hdZ); hdZ = fma((double)az.w, h23.y, hdZ);
      hdN = fma((double)an.x, h01.x, hdN); hdN = fma((double)an.y, h01.y, hdN);
      hdN = fma((double)an.z, h23.x, hdN); hdN = fma((double)an.w, h23.y, hdN);
      xdR = fma((double)br.x, x01.x, xdR); xdR = fma((double)br.y, x01.y, xdR);
      xdR = fma((double)br.z, x23.x, xdR); xdR = fma((double)br.w, x23.y, xdR);
      xdZ = fma((double)bz.x, x01.x, xdZ); xdZ = fma((double)bz.y, x01.y, xdZ);
      xdZ = fma((double)bz.z, x23.x, xdZ); xdZ = fma((double)bz.w, x23.y, xdZ);
      xdN = fma((double)bn.x, x01.x, xdN); xdN = fma((double)bn.y, x01.y, xdN);
      xdN = fma((double)bn.z, x23.x, xdN); xdN = fma((double)bn.w, x23.y, xdN);
    }
    // quad reduce over q (lanes xor 1, 2) — all 4 lanes get identical sums
    hdR += __shfl_xor(hdR, 1, 64); hdR += __shfl_xor(hdR, 2, 64);
    hdZ += __shfl_xor(hdZ, 1, 64); hdZ += __shfl_xor(hdZ, 2, 64);
    hdN += __shfl_xor(hdN, 1, 64); hdN += __shfl_xor(hdN, 2, 64);
    xdR += __shfl_xor(xdR, 1, 64); xdR += __shfl_xor(xdR, 2, 64);
    xdZ += __shfl_xor(xdZ, 1, 64); xdZ += __shfl_xor(xdZ, 2, 64);
    xdN += __shfl_xor(xdN, 1, 64); xdN += __shfl_xor(xdN, 2, 64);

    // gates: all lanes, redundant over q (bitwise identical)
    double r  = 1.0/(1.0 + exp_d(-((xdR + hdR) + bR)));
    double z  = 1.0/(1.0 + exp_d(-((xdZ + hdZ) + bZ)));
    double yn = (xdN + biN) + r*(hdN + bhN);
    double nn = 1.0 - 2.0/(exp_d(2.0*yn) + 1.0);
    h = (1.0 - z)*nn + z*h;

    if (q == 0){
      hsh[nxt][j + 2*(j>>4)] = h;
      qout[(size_t)t*NB*64] = (_Float16)(float)h;   // one-shot rounding
    }
    if (tid < 64){
      xsh[nxt][tid + 2*(tid>>4)] = (double)xc0;     // x[t+1]
      int tp = (t+3 < TSTEPS) ? (t+3) : (TSTEPS-1);
      float xnx = xp[(size_t)tp*NB*64];
      xc0 = xc1; xc1 = xnx;
    }
    __syncthreads();
  }

  if (q == 0)
    out_state[(size_t)(g*512 + n)*64 + j] = (float)h;
}

// ---------------------------------------------------------------------------
// Attention + output projection (unchanged — output 0 passed with it).
// One wave per (t,b) tile; mfma_f32_32x32x16_f16; f32 output.
// ---------------------------------------------------------------------------
__global__ __launch_bounds__(64) void attn(
    const _Float16* __restrict__ qkv,        // [3,500,512,64] f16
    const float* __restrict__ w_o,           // [64,64] f32
    const float* __restrict__ b_o,           // [64] f32
    float* __restrict__ out)                 // [500,16,32,64] f32
{
  __shared__ __align__(16) _Float16 Qs[32*72];
  __shared__ __align__(16) _Float16 Ks[32*72];
  __shared__ __align__(16) _Float16 Vt[64*40];
  __shared__ __align__(16) _Float16 Wm[32*40];
  __shared__ __align__(16) _Float16 wols[64*72];
  __shared__ float bo[64];

  const int lane = threadIdx.x;
  const int t = blockIdx.x >> 4;
  const int b = blockIdx.x & 15;
  const size_t base    = ((size_t)t*NB + b*32)*64;
  const size_t gstride = (size_t)TSTEPS*NB*64;

  #pragma unroll
  for (int it=0; it<4; ++it){
    int idx = it*64 + lane;
    int f = idx >> 3, ko = (idx & 7)*8;
    *(f16x8*)&Qs[f*72+ko] = *(const f16x8*)&qkv[base + (size_t)f*64 + ko];
    *(f16x8*)&Ks[f*72+ko] = *(const f16x8*)&qkv[gstride + base + (size_t)f*64 + ko];
  }
  #pragma unroll
  for (int it=0; it<32; ++it){
    int idx = it*64 + lane;
    int f = idx >> 6, hh = idx & 63;
    Vt[hh*40 + f] = qkv[2*gstride + base + (size_t)f*64 + hh];
  }
  #pragma unroll
  for (int it=0; it<32; ++it){
    int idx = it*64 + lane;
    int c = idx >> 5, hp = (idx & 31)*2;
    float2 u = *(const float2*)(w_o + c*64 + hp);
    wols[c*72 + hp]     = (_Float16)u.x;
    wols[c*72 + hp + 1] = (_Float16)u.y;
  }
  bo[lane] = b_o[lane];

  const int m  = lane & 31;
  const int hk = (lane >> 5) * 8;
  const int rbase = (lane >> 5) * 4;

  // ---- W = Q @ K^T ----
  f32x16 accW;
  #pragma unroll
  for (int i=0;i<16;++i) accW[i]=0.f;
  #pragma unroll
  for (int kb=0; kb<4; ++kb){
    f16x8 a  = *(const f16x8*)&Qs[m*72 + kb*16 + hk];
    f16x8 bb = *(const f16x8*)&Ks[m*72 + kb*16 + hk];
    accW = __builtin_amdgcn_mfma_f32_32x32x16_f16(a, bb, accW, 0, 0, 0);
  }
  #pragma unroll
  for (int r=0; r<16; ++r){
    int row = (r&3) + 8*(r>>2) + rbase;
    Wm[row*40 + m] = (_Float16)accW[r];
  }

  // ---- A = W @ V ----
  f32x16 accA0, accA1;
  #pragma unroll
  for (int i=0;i<16;++i){ accA0[i]=0.f; accA1[i]=0.f; }
  #pragma unroll
  for (int kb=0; kb<2; ++kb){
    f16x8 a  = *(const f16x8*)&Wm[m*40 + kb*16 + hk];
    f16x8 b0 = *(const f16x8*)&Vt[(     m)*40 + kb*16 + hk];
    f16x8 b1 = *(const f16x8*)&Vt[(32 + m)*40 + kb*16 + hk];
    accA0 = __builtin_amdgcn_mfma_f32_32x32x16_f16(a, b0, accA0, 0, 0, 0);
    accA1 = __builtin_amdgcn_mfma_f32_32x32x16_f16(a, b1, accA1, 0, 0, 0);
  }

  // ---- softmax over f ----
  float mx0 = accA0[0], mx1 = accA1[0];
  #pragma unroll
  for (int r=1;r<16;++r){ mx0 = fmaxf(mx0, accA0[r]); mx1 = fmaxf(mx1, accA1[r]); }
  mx0 = fmaxf(mx0, __shfl_xor(mx0, 32, 64));
  mx1 = fmaxf(mx1, __shfl_xor(mx1, 32, 64));
  float s0 = 0.f, s1 = 0.f;
  #pragma unroll
  for (int r=0;r<16;++r){
    float e0 = __builtin_amdgcn_exp2f(LOG2E*(accA0[r]-mx0)); accA0[r]=e0; s0+=e0;
    float e1 = __builtin_amdgcn_exp2f(LOG2E*(accA1[r]-mx1)); accA1[r]=e1; s1+=e1;
  }
  s0 += __shfl_xor(s0, 32, 64);
  s1 += __shfl_xor(s1, 32, 64);
  float i0 = __builtin_amdgcn_rcpf(s0), i1 = __builtin_amdgcn_rcpf(s1);
  #pragma unroll
  for (int r=0;r<16;++r){
    int row = (r&3) + 8*(r>>2) + rbase;
    Qs[row*72 + m]      = (_Float16)(accA0[r]*i0);
    Qs[row*72 + 32 + m] = (_Float16)(accA1[r]*i1);
  }

  // ---- O = P @ w_o^T + b_o ----
  f32x16 accO0, accO1;
  #pragma unroll
  for (int i=0;i<16;++i){ accO0[i]=0.f; accO1[i]=0.f; }
  #pragma unroll
  for (int kb=0; kb<4; ++kb){
    f16x8 a  = *(const f16x8*)&Qs[m*72 + kb*16 + hk];
    f16x8 b0 = *(const f16x8*)&wols[(     m)*72 + kb*16 + hk];
    f16x8 b1 = *(const f16x8*)&wols[(32 + m)*72 + kb*16 + hk];
    accO0 = __builtin_amdgcn_mfma_f32_32x32x16_f16(a, b0, accO0, 0, 0, 0);
    accO1 = __builtin_amdgcn_mfma_f32_32x32x16_f16(a, b1, accO1, 0, 0, 0);
  }
  const size_t obase = ((size_t)t*16 + b)*2048;
  #pragma unroll
  for (int r=0;r<16;++r){
    int row = (r&3) + 8*(r>>2) + rbase;
    out[obase + row*64 + m]      = accO0[r] + bo[m];
    out[obase + row*64 + 32 + m] = accO1[r] + bo[32+m];
  }
}

// ---------------------------------------------------------------------------
extern "C" void kernel_launch(void* const* d_in, const int* in_sizes, int n_in,
                              void* d_out, int out_size, void* d_ws, size_t ws_size,
                              hipStream_t stream)
{
  const float* x  = (const float*)d_in[0];
  const float* st = (const float*)d_in[1];
  _Float16* qkv = (_Float16*)d_ws;   // 98,304,000 B (fits)
  float* out = (float*)d_out;
  float* out_state = out + (size_t)16384000;

  gru_f64<<<dim3(1536), dim3(256), 0, stream>>>(
    x, st,
    (const float*)d_in[2],  (const float*)d_in[3],
    (const float*)d_in[4],  (const float*)d_in[5],
    (const float*)d_in[6],  (const float*)d_in[7],
    (const float*)d_in[8],  (const float*)d_in[9],
    (const float*)d_in[10], (const float*)d_in[11],
    (const float*)d_in[12], (const float*)d_in[13],
    qkv, out_state);

  attn<<<dim3(8000), dim3(64), 0, stream>>>(
    qkv, (const float*)d_in[14], (const float*)d_in[15], out);
}

// Round 3
// 2283.348 us; speedup vs baseline: 5.5074x; 5.5074x over previous
//
#include <hip/hip_runtime.h>

typedef _Float16 f16x8  __attribute__((ext_vector_type(8)));
typedef float    f32x16 __attribute__((ext_vector_type(16)));

#define TSTEPS 500
#define NB 512
#define LOG2E 1.442695041f

// f64 exp, Cody-Waite reduction + degree-11 Taylor, rel err ~1e-15.
__device__ __forceinline__ double exp_d(double v){
  v = fmin(fmax(v, -700.0), 700.0);
  double t = v * 1.4426950408889634;           // v / ln2
  double n = rint(t);
  double f = fma(-n, 6.931471803691238e-01, v);   // LN2_HI
  f = fma(-n, 1.9082149292705877e-10, f);         // LN2_LO
  double p = 2.5052108385441718e-08;           // 1/11!
  p = fma(p, f, 2.7557319223985893e-07);       // 1/10!
  p = fma(p, f, 2.7557319223985888e-06);       // 1/9!
  p = fma(p, f, 2.4801587301587302e-05);       // 1/8!
  p = fma(p, f, 1.9841269841269841e-04);       // 1/7!
  p = fma(p, f, 1.3888888888888889e-03);       // 1/6!
  p = fma(p, f, 8.3333333333333332e-03);       // 1/5!
  p = fma(p, f, 4.1666666666666664e-02);       // 1/4!
  p = fma(p, f, 1.6666666666666666e-01);       // 1/3!
  p = fma(p, f, 0.5);
  p = fma(p, f, 1.0);
  p = fma(p, f, 1.0);
  long long bits = (1023LL + (long long)n) << 52;
  return p * __longlong_as_double(bits);
}

// ---------------------------------------------------------------------------
// Fused GRU, 256 threads (4 waves) per (g,n) sequence.
// Column-split: thread (j=tid>>2, q=tid&3) owns rows {j,64+j,128+j} of W_ih
// and W_hh over cols [16q,16q+16) -> 96 weight VGPRs, 16 ds_read_b128/step.
// Quad shfl_xor reduces the 4 column-partials; gates computed by ALL lanes
// (redundant over q, bitwise identical) -> one barrier per step.
// LAUNCH BOUNDS: (256,2). Round-2's (256,3) made the allocator clamp to 84
// VGPRs and spill all 96 weight regs to scratch -> 26 GB HBM fetch, 2x
// regression. (256,2) caps at 256 VGPR; natural demand ~150 -> no spill,
// and HW still fits 3 waves/SIMD at <=170 VGPRs.
// ---------------------------------------------------------------------------
__global__ __launch_bounds__(256, 2) void gru_f64(
    const float* __restrict__ x,    // [500,512,64] f32
    const float* __restrict__ st,   // [3,512,64] f32
    const float* __restrict__ wih0, const float* __restrict__ whh0,
    const float* __restrict__ bih0, const float* __restrict__ bhh0,
    const float* __restrict__ wih1, const float* __restrict__ whh1,
    const float* __restrict__ bih1, const float* __restrict__ bhh1,
    const float* __restrict__ wih2, const float* __restrict__ whh2,
    const float* __restrict__ bih2, const float* __restrict__ bhh2,
    _Float16* __restrict__ qkv,      // ws: [3,500,512,64] f16
    float* __restrict__ out_state)   // [3,512,64] f32
{
  __shared__ __align__(16) double hsh[2][72];
  __shared__ __align__(16) double xsh[2][72];

  const int tid = threadIdx.x;
  const int j = tid >> 2;            // h-index 0..63
  const int q = tid & 3;             // column quarter
  const int g = blockIdx.x >> 9;
  const int n = blockIdx.x & 511;

  const float* wih = (g==0) ? wih0 : ((g==1) ? wih1 : wih2);
  const float* whh = (g==0) ? whh0 : ((g==1) ? whh1 : whh2);
  const float* bih = (g==0) ? bih0 : ((g==1) ? bih1 : bih2);
  const float* bhh = (g==0) ? bhh0 : ((g==1) ? bhh1 : bhh2);

  // 96 VGPRs of f32 weights: rows j(r), 64+j(z), 128+j(n); cols [16q,16q+16)
  // Lane tid reads floats [16*tid .. 16*tid+15] -> perfectly coalesced.
  float4 wiR[4], wiZ[4], wiN[4], whR[4], whZ[4], whN[4];
  {
    const float4* pR = (const float4*)(wih + (size_t)(       j)*64 + q*16);
    const float4* pZ = (const float4*)(wih + (size_t)( 64 + j)*64 + q*16);
    const float4* pN = (const float4*)(wih + (size_t)(128 + j)*64 + q*16);
    const float4* rR = (const float4*)(whh + (size_t)(       j)*64 + q*16);
    const float4* rZ = (const float4*)(whh + (size_t)( 64 + j)*64 + q*16);
    const float4* rN = (const float4*)(whh + (size_t)(128 + j)*64 + q*16);
    #pragma unroll
    for (int k=0;k<4;++k){
      wiR[k]=pR[k]; wiZ[k]=pZ[k]; wiN[k]=pN[k];
      whR[k]=rR[k]; whZ[k]=rZ[k]; whN[k]=rN[k];
    }
  }
  const double bR  = (double)bih[j]      + (double)bhh[j];      // r: bi+bh fold
  const double bZ  = (double)bih[64+j]   + (double)bhh[64+j];   // z: bi+bh fold
  const double biN = (double)bih[128+j];
  const double bhN = (double)bhh[128+j];

  double h = (double)st[(size_t)(g*512 + n)*64 + j];   // redundant across q

  const float* xp = x + (size_t)n*64 + tid;            // loader lanes tid<64
  float xc0 = 0.f, xc1 = 0.f;
  if (tid < 64){
    int ci = tid + 2*(tid>>4);
    hsh[0][ci] = (double)st[(size_t)(g*512 + n)*64 + tid];
    xsh[0][ci] = (double)xp[0];
    xc0 = xp[(size_t)NB*64];
    xc1 = xp[(size_t)2*NB*64];
  }
  _Float16* qout = qkv + ((size_t)g*TSTEPS*NB + n)*64 + j;
  __syncthreads();

  for (int t=0; t<TSTEPS; ++t){
    const int cur = t & 1, nxt = cur ^ 1;
    const double2* hp = (const double2*)(&hsh[cur][18*q]);  // 144B-aligned
    const double2* xq = (const double2*)(&xsh[cur][18*q]);

    double hdR=0.0, hdZ=0.0, hdN=0.0, xdR=0.0, xdZ=0.0, xdN=0.0;
    #pragma unroll
    for (int w=0; w<4; ++w){
      double2 h01 = hp[2*w], h23 = hp[2*w+1];
      double2 x01 = xq[2*w], x23 = xq[2*w+1];
      float4 ar = whR[w], az = whZ[w], an = whN[w];
      float4 br = wiR[w], bz = wiZ[w], bn = wiN[w];
      hdR = fma((double)ar.x, h01.x, hdR); hdR = fma((double)ar.y, h01.y, hdR);
      hdR = fma((double)ar.z, h23.x, hdR); hdR = fma((double)ar.w, h23.y, hdR);
      hdZ = fma((double)az.x, h01.x, hdZ); hdZ = fma((double)az.y, h01.y, hdZ);
      hdZ = fma((double)az.z, h23.x, hdZ); hdZ = fma((double)az.w, h23.y, hdZ);
      hdN = fma((double)an.x, h01.x, hdN); hdN = fma((double)an.y, h01.y, hdN);
      hdN = fma((double)an.z, h23.x, hdN); hdN = fma((double)an.w, h23.y, hdN);
      xdR = fma((double)br.x, x01.x, xdR); xdR = fma((double)br.y, x01.y, xdR);
      xdR = fma((double)br.z, x23.x, xdR); xdR = fma((double)br.w, x23.y, xdR);
      xdZ = fma((double)bz.x, x01.x, xdZ); xdZ = fma((double)bz.y, x01.y, xdZ);
      xdZ = fma((double)bz.z, x23.x, xdZ); xdZ = fma((double)bz.w, x23.y, xdZ);
      xdN = fma((double)bn.x, x01.x, xdN); xdN = fma((double)bn.y, x01.y, xdN);
      xdN = fma((double)bn.z, x23.x, xdN); xdN = fma((double)bn.w, x23.y, xdN);
    }
    // quad reduce over q (lanes xor 1, 2) — all 4 lanes get identical sums
    hdR += __shfl_xor(hdR, 1, 64); hdR += __shfl_xor(hdR, 2, 64);
    hdZ += __shfl_xor(hdZ, 1, 64); hdZ += __shfl_xor(hdZ, 2, 64);
    hdN += __shfl_xor(hdN, 1, 64); hdN += __shfl_xor(hdN, 2, 64);
    xdR += __shfl_xor(xdR, 1, 64); xdR += __shfl_xor(xdR, 2, 64);
    xdZ += __shfl_xor(xdZ, 1, 64); xdZ += __shfl_xor(xdZ, 2, 64);
    xdN += __shfl_xor(xdN, 1, 64); xdN += __shfl_xor(xdN, 2, 64);

    // gates: all lanes, redundant over q (bitwise identical)
    double r  = 1.0/(1.0 + exp_d(-((xdR + hdR) + bR)));
    double z  = 1.0/(1.0 + exp_d(-((xdZ + hdZ) + bZ)));
    double yn = (xdN + biN) + r*(hdN + bhN);
    double nn = 1.0 - 2.0/(exp_d(2.0*yn) + 1.0);
    h = (1.0 - z)*nn + z*h;

    if (q == 0){
      hsh[nxt][j + 2*(j>>4)] = h;
      qout[(size_t)t*NB*64] = (_Float16)(float)h;   // one-shot rounding
    }
    if (tid < 64){
      xsh[nxt][tid + 2*(tid>>4)] = (double)xc0;     // x[t+1]
      int tp = (t+3 < TSTEPS) ? (t+3) : (TSTEPS-1);
      float xnx = xp[(size_t)tp*NB*64];
      xc0 = xc1; xc1 = xnx;
    }
    __syncthreads();
  }

  if (q == 0)
    out_state[(size_t)(g*512 + n)*64 + j] = (float)h;
}

// ---------------------------------------------------------------------------
// Attention + output projection (unchanged — output 0 passed with it).
// One wave per (t,b) tile; mfma_f32_32x32x16_f16; f32 output.
// ---------------------------------------------------------------------------
__global__ __launch_bounds__(64) void attn(
    const _Float16* __restrict__ qkv,        // [3,500,512,64] f16
    const float* __restrict__ w_o,           // [64,64] f32
    const float* __restrict__ b_o,           // [64] f32
    float* __restrict__ out)                 // [500,16,32,64] f32
{
  __shared__ __align__(16) _Float16 Qs[32*72];
  __shared__ __align__(16) _Float16 Ks[32*72];
  __shared__ __align__(16) _Float16 Vt[64*40];
  __shared__ __align__(16) _Float16 Wm[32*40];
  __shared__ __align__(16) _Float16 wols[64*72];
  __shared__ float bo[64];

  const int lane = threadIdx.x;
  const int t = blockIdx.x >> 4;
  const int b = blockIdx.x & 15;
  const size_t base    = ((size_t)t*NB + b*32)*64;
  const size_t gstride = (size_t)TSTEPS*NB*64;

  #pragma unroll
  for (int it=0; it<4; ++it){
    int idx = it*64 + lane;
    int f = idx >> 3, ko = (idx & 7)*8;
    *(f16x8*)&Qs[f*72+ko] = *(const f16x8*)&qkv[base + (size_t)f*64 + ko];
    *(f16x8*)&Ks[f*72+ko] = *(const f16x8*)&qkv[gstride + base + (size_t)f*64 + ko];
  }
  #pragma unroll
  for (int it=0; it<32; ++it){
    int idx = it*64 + lane;
    int f = idx >> 6, hh = idx & 63;
    Vt[hh*40 + f] = qkv[2*gstride + base + (size_t)f*64 + hh];
  }
  #pragma unroll
  for (int it=0; it<32; ++it){
    int idx = it*64 + lane;
    int c = idx >> 5, hp = (idx & 31)*2;
    float2 u = *(const float2*)(w_o + c*64 + hp);
    wols[c*72 + hp]     = (_Float16)u.x;
    wols[c*72 + hp + 1] = (_Float16)u.y;
  }
  bo[lane] = b_o[lane];

  const int m  = lane & 31;
  const int hk = (lane >> 5) * 8;
  const int rbase = (lane >> 5) * 4;

  // ---- W = Q @ K^T ----
  f32x16 accW;
  #pragma unroll
  for (int i=0;i<16;++i) accW[i]=0.f;
  #pragma unroll
  for (int kb=0; kb<4; ++kb){
    f16x8 a  = *(const f16x8*)&Qs[m*72 + kb*16 + hk];
    f16x8 bb = *(const f16x8*)&Ks[m*72 + kb*16 + hk];
    accW = __builtin_amdgcn_mfma_f32_32x32x16_f16(a, bb, accW, 0, 0, 0);
  }
  #pragma unroll
  for (int r=0; r<16; ++r){
    int row = (r&3) + 8*(r>>2) + rbase;
    Wm[row*40 + m] = (_Float16)accW[r];
  }

  // ---- A = W @ V ----
  f32x16 accA0, accA1;
  #pragma unroll
  for (int i=0;i<16;++i){ accA0[i]=0.f; accA1[i]=0.f; }
  #pragma unroll
  for (int kb=0; kb<2; ++kb){
    f16x8 a  = *(const f16x8*)&Wm[m*40 + kb*16 + hk];
    f16x8 b0 = *(const f16x8*)&Vt[(     m)*40 + kb*16 + hk];
    f16x8 b1 = *(const f16x8*)&Vt[(32 + m)*40 + kb*16 + hk];
    accA0 = __builtin_amdgcn_mfma_f32_32x32x16_f16(a, b0, accA0, 0, 0, 0);
    accA1 = __builtin_amdgcn_mfma_f32_32x32x16_f16(a, b1, accA1, 0, 0, 0);
  }

  // ---- softmax over f ----
  float mx0 = accA0[0], mx1 = accA1[0];
  #pragma unroll
  for (int r=1;r<16;++r){ mx0 = fmaxf(mx0, accA0[r]); mx1 = fmaxf(mx1, accA1[r]); }
  mx0 = fmaxf(mx0, __shfl_xor(mx0, 32, 64));
  mx1 = fmaxf(mx1, __shfl_xor(mx1, 32, 64));
  float s0 = 0.f, s1 = 0.f;
  #pragma unroll
  for (int r=0;r<16;++r){
    float e0 = __builtin_amdgcn_exp2f(LOG2E*(accA0[r]-mx0)); accA0[r]=e0; s0+=e0;
    float e1 = __builtin_amdgcn_exp2f(LOG2E*(accA1[r]-mx1)); accA1[r]=e1; s1+=e1;
  }
  s0 += __shfl_xor(s0, 32, 64);
  s1 += __shfl_xor(s1, 32, 64);
  float i0 = __builtin_amdgcn_rcpf(s0), i1 = __builtin_amdgcn_rcpf(s1);
  #pragma unroll
  for (int r=0;r<16;++r){
    int row = (r&3) + 8*(r>>2) + rbase;
    Qs[row*72 + m]      = (_Float16)(accA0[r]*i0);
    Qs[row*72 + 32 + m] = (_Float16)(accA1[r]*i1);
  }

  // ---- O = P @ w_o^T + b_o ----
  f32x16 accO0, accO1;
  #pragma unroll
  for (int i=0;i<16;++i){ accO0[i]=0.f; accO1[i]=0.f; }
  #pragma unroll
  for (int kb=0; kb<4; ++kb){
    f16x8 a  = *(const f16x8*)&Qs[m*72 + kb*16 + hk];
    f16x8 b0 = *(const f16x8*)&wols[(     m)*72 + kb*16 + hk];
    f16x8 b1 = *(const f16x8*)&wols[(32 + m)*72 + kb*16 + hk];
    accO0 = __builtin_amdgcn_mfma_f32_32x32x16_f16(a, b0, accO0, 0, 0, 0);
    accO1 = __builtin_amdgcn_mfma_f32_32x32x16_f16(a, b1, accO1, 0, 0, 0);
  }
  const size_t obase = ((size_t)t*16 + b)*2048;
  #pragma unroll
  for (int r=0;r<16;++r){
    int row = (r&3) + 8*(r>>2) + rbase;
    out[obase + row*64 + m]      = accO0[r] + bo[m];
    out[obase + row*64 + 32 + m] = accO1[r] + bo[32+m];
  }
}

// ---------------------------------------------------------------------------
extern "C" void kernel_launch(void* const* d_in, const int* in_sizes, int n_in,
                              void* d_out, int out_size, void* d_ws, size_t ws_size,
                              hipStream_t stream)
{
  const float* x  = (const float*)d_in[0];
  const float* st = (const float*)d_in[1];
  _Float16* qkv = (_Float16*)d_ws;   // 98,304,000 B (fits)
  float* out = (float*)d_out;
  float* out_state = out + (size_t)16384000;

  gru_f64<<<dim3(1536), dim3(256), 0, stream>>>(
    x, st,
    (const float*)d_in[2],  (const float*)d_in[3],
    (const float*)d_in[4],  (const float*)d_in[5],
    (const float*)d_in[6],  (const float*)d_in[7],
    (const float*)d_in[8],  (const float*)d_in[9],
    (const float*)d_in[10], (const float*)d_in[11],
    (const float*)d_in[12], (const float*)d_in[13],
    qkv, out_state);

  attn<<<dim3(8000), dim3(64), 0, stream>>>(
    qkv, (const float*)d_in[14], (const float*)d_in[15], out);
}

// Round 4
// 2252.551 us; speedup vs baseline: 5.5827x; 1.0137x over previous
//
#include <hip/hip_runtime.h>

typedef _Float16 f16x8  __attribute__((ext_vector_type(8)));
typedef float    f32x16 __attribute__((ext_vector_type(16)));

#define TSTEPS 500
#define NB 512
#define LOG2E 1.442695041f

// f64 exp, Cody-Waite reduction + degree-11 Taylor, rel err ~1e-15.
__device__ __forceinline__ double exp_d(double v){
  v = fmin(fmax(v, -700.0), 700.0);
  double t = v * 1.4426950408889634;           // v / ln2
  double n = rint(t);
  double f = fma(-n, 6.931471803691238e-01, v);   // LN2_HI
  f = fma(-n, 1.9082149292705877e-10, f);         // LN2_LO
  double p = 2.5052108385441718e-08;           // 1/11!
  p = fma(p, f, 2.7557319223985893e-07);       // 1/10!
  p = fma(p, f, 2.7557319223985888e-06);       // 1/9!
  p = fma(p, f, 2.4801587301587302e-05);       // 1/8!
  p = fma(p, f, 1.9841269841269841e-04);       // 1/7!
  p = fma(p, f, 1.3888888888888889e-03);       // 1/6!
  p = fma(p, f, 8.3333333333333332e-03);       // 1/5!
  p = fma(p, f, 4.1666666666666664e-02);       // 1/4!
  p = fma(p, f, 1.6666666666666666e-01);       // 1/3!
  p = fma(p, f, 0.5);
  p = fma(p, f, 1.0);
  p = fma(p, f, 1.0);
  long long bits = (1023LL + (long long)n) << 52;
  return p * __longlong_as_double(bits);
}

// ---------------------------------------------------------------------------
// Fused GRU, 256 threads (4 waves) per (g,n) sequence.
// Column-split: thread (j=tid>>2, q=tid&3) owns rows {j,64+j,128+j} of W_ih
// and W_hh over cols [16q,16q+16). R4 change: weights held as F64 IN
// REGISTERS (192 VGPR), converted ONCE at startup — R3 profiling showed the
// per-step v_cvt_f64_f32 of all 96 weight elements was ~25-35% of total
// VALU issue. Biases folded into accumulator init (q==0 lane only, so the
// quad-reduce adds each bias exactly once). 16 ds_read_b128/step, quad
// shfl_xor reduce, gates on all lanes (one issue per wave), 1 barrier/step.
// Register budget: 192 wt + ~55 working ≈ 250 <= 256 cap from (256,2);
// measured occupancy was already at the 2-waves/SIMD level so no loss.
// TRIPWIRE: FETCH_SIZE > 0.5 GB here means the allocator spilled weights
// (round-2 failure mode) -> fall back to W_hh-f64/W_ih-f32 hybrid.
// ---------------------------------------------------------------------------
__global__ __launch_bounds__(256, 2) void gru_f64(
    const float* __restrict__ x,    // [500,512,64] f32
    const float* __restrict__ st,   // [3,512,64] f32
    const float* __restrict__ wih0, const float* __restrict__ whh0,
    const float* __restrict__ bih0, const float* __restrict__ bhh0,
    const float* __restrict__ wih1, const float* __restrict__ whh1,
    const float* __restrict__ bih1, const float* __restrict__ bhh1,
    const float* __restrict__ wih2, const float* __restrict__ whh2,
    const float* __restrict__ bih2, const float* __restrict__ bhh2,
    _Float16* __restrict__ qkv,      // ws: [3,500,512,64] f16
    float* __restrict__ out_state)   // [3,512,64] f32
{
  __shared__ __align__(16) double hsh[2][72];
  __shared__ __align__(16) double xsh[2][72];

  const int tid = threadIdx.x;
  const int j = tid >> 2;            // h-index 0..63
  const int q = tid & 3;             // column quarter
  const int g = blockIdx.x >> 9;
  const int n = blockIdx.x & 511;

  const float* wih = (g==0) ? wih0 : ((g==1) ? wih1 : wih2);
  const float* whh = (g==0) ? whh0 : ((g==1) ? whh1 : whh2);
  const float* bih = (g==0) ? bih0 : ((g==1) ? bih1 : bih2);
  const float* bhh = (g==0) ? bhh0 : ((g==1) ? bhh1 : bhh2);

  // 192 VGPRs of f64 weights (converted once): rows j(r), 64+j(z), 128+j(n);
  // cols [16q,16q+16). Loads are float4, perfectly coalesced per lane.
  double wiR[16], wiZ[16], wiN[16], whR[16], whZ[16], whN[16];
  {
    const float4* pR = (const float4*)(wih + (size_t)(       j)*64 + q*16);
    const float4* pZ = (const float4*)(wih + (size_t)( 64 + j)*64 + q*16);
    const float4* pN = (const float4*)(wih + (size_t)(128 + j)*64 + q*16);
    const float4* rR = (const float4*)(whh + (size_t)(       j)*64 + q*16);
    const float4* rZ = (const float4*)(whh + (size_t)( 64 + j)*64 + q*16);
    const float4* rN = (const float4*)(whh + (size_t)(128 + j)*64 + q*16);
    #pragma unroll
    for (int k=0;k<4;++k){
      float4 a;
      a = pR[k]; wiR[4*k]=(double)a.x; wiR[4*k+1]=(double)a.y; wiR[4*k+2]=(double)a.z; wiR[4*k+3]=(double)a.w;
      a = pZ[k]; wiZ[4*k]=(double)a.x; wiZ[4*k+1]=(double)a.y; wiZ[4*k+2]=(double)a.z; wiZ[4*k+3]=(double)a.w;
      a = pN[k]; wiN[4*k]=(double)a.x; wiN[4*k+1]=(double)a.y; wiN[4*k+2]=(double)a.z; wiN[4*k+3]=(double)a.w;
      a = rR[k]; whR[4*k]=(double)a.x; whR[4*k+1]=(double)a.y; whR[4*k+2]=(double)a.z; whR[4*k+3]=(double)a.w;
      a = rZ[k]; whZ[4*k]=(double)a.x; whZ[4*k+1]=(double)a.y; whZ[4*k+2]=(double)a.z; whZ[4*k+3]=(double)a.w;
      a = rN[k]; whN[4*k]=(double)a.x; whN[4*k+1]=(double)a.y; whN[4*k+2]=(double)a.z; whN[4*k+3]=(double)a.w;
    }
  }
  // Biases, folded into accumulator init on the q==0 lane only (so the quad
  // reduce sums each bias exactly once). r/z: b_ih+b_hh folded together.
  const double bRi  = (q==0) ? ((double)bih[j]    + (double)bhh[j]   ) : 0.0;
  const double bZi  = (q==0) ? ((double)bih[64+j] + (double)bhh[64+j]) : 0.0;
  const double biNi = (q==0) ? (double)bih[128+j] : 0.0;
  const double bhNi = (q==0) ? (double)bhh[128+j] : 0.0;

  double h = (double)st[(size_t)(g*512 + n)*64 + j];   // redundant across q

  const float* xp = x + (size_t)n*64 + tid;            // loader lanes tid<64
  float xc0 = 0.f, xc1 = 0.f;
  if (tid < 64){
    int ci = tid + 2*(tid>>4);
    hsh[0][ci] = (double)st[(size_t)(g*512 + n)*64 + tid];
    xsh[0][ci] = (double)xp[0];
    xc0 = xp[(size_t)NB*64];
    xc1 = xp[(size_t)2*NB*64];
  }
  _Float16* qout = qkv + ((size_t)g*TSTEPS*NB + n)*64 + j;
  __syncthreads();

  for (int t=0; t<TSTEPS; ++t){
    const int cur = t & 1, nxt = cur ^ 1;
    const double2* hp = (const double2*)(&hsh[cur][18*q]);  // 144B-aligned
    const double2* xq = (const double2*)(&xsh[cur][18*q]);

    double hdR=bRi, hdZ=bZi, hdN=bhNi, xdR=0.0, xdZ=0.0, xdN=biNi;
    #pragma unroll
    for (int w=0; w<4; ++w){
      double2 h01 = hp[2*w], h23 = hp[2*w+1];
      double2 x01 = xq[2*w], x23 = xq[2*w+1];
      hdR = fma(whR[4*w+0], h01.x, hdR); hdR = fma(whR[4*w+1], h01.y, hdR);
      hdR = fma(whR[4*w+2], h23.x, hdR); hdR = fma(whR[4*w+3], h23.y, hdR);
      hdZ = fma(whZ[4*w+0], h01.x, hdZ); hdZ = fma(whZ[4*w+1], h01.y, hdZ);
      hdZ = fma(whZ[4*w+2], h23.x, hdZ); hdZ = fma(whZ[4*w+3], h23.y, hdZ);
      hdN = fma(whN[4*w+0], h01.x, hdN); hdN = fma(whN[4*w+1], h01.y, hdN);
      hdN = fma(whN[4*w+2], h23.x, hdN); hdN = fma(whN[4*w+3], h23.y, hdN);
      xdR = fma(wiR[4*w+0], x01.x, xdR); xdR = fma(wiR[4*w+1], x01.y, xdR);
      xdR = fma(wiR[4*w+2], x23.x, xdR); xdR = fma(wiR[4*w+3], x23.y, xdR);
      xdZ = fma(wiZ[4*w+0], x01.x, xdZ); xdZ = fma(wiZ[4*w+1], x01.y, xdZ);
      xdZ = fma(wiZ[4*w+2], x23.x, xdZ); xdZ = fma(wiZ[4*w+3], x23.y, xdZ);
      xdN = fma(wiN[4*w+0], x01.x, xdN); xdN = fma(wiN[4*w+1], x01.y, xdN);
      xdN = fma(wiN[4*w+2], x23.x, xdN); xdN = fma(wiN[4*w+3], x23.y, xdN);
    }
    // quad reduce over q (lanes xor 1, 2) — all 4 lanes get identical sums
    hdR += __shfl_xor(hdR, 1, 64); hdR += __shfl_xor(hdR, 2, 64);
    hdZ += __shfl_xor(hdZ, 1, 64); hdZ += __shfl_xor(hdZ, 2, 64);
    hdN += __shfl_xor(hdN, 1, 64); hdN += __shfl_xor(hdN, 2, 64);
    xdR += __shfl_xor(xdR, 1, 64); xdR += __shfl_xor(xdR, 2, 64);
    xdZ += __shfl_xor(xdZ, 1, 64); xdZ += __shfl_xor(xdZ, 2, 64);
    xdN += __shfl_xor(xdN, 1, 64); xdN += __shfl_xor(xdN, 2, 64);

    // gates: all lanes, redundant over q (bitwise identical, one issue/wave)
    double r  = 1.0/(1.0 + exp_d(-(xdR + hdR)));
    double z  = 1.0/(1.0 + exp_d(-(xdZ + hdZ)));
    double yn = xdN + r*hdN;                   // biases already inside sums
    double nn = 1.0 - 2.0/(exp_d(2.0*yn) + 1.0);
    h = (1.0 - z)*nn + z*h;

    if (q == 0){
      hsh[nxt][j + 2*(j>>4)] = h;
      qout[(size_t)t*NB*64] = (_Float16)(float)h;   // one-shot rounding
    }
    if (tid < 64){
      xsh[nxt][tid + 2*(tid>>4)] = (double)xc0;     // x[t+1]
      int tp = (t+3 < TSTEPS) ? (t+3) : (TSTEPS-1);
      float xnx = xp[(size_t)tp*NB*64];
      xc0 = xc1; xc1 = xnx;
    }
    __syncthreads();
  }

  if (q == 0)
    out_state[(size_t)(g*512 + n)*64 + j] = (float)h;
}

// ---------------------------------------------------------------------------
// Attention + output projection (unchanged — output 0 passed with it).
// One wave per (t,b) tile; mfma_f32_32x32x16_f16; f32 output.
// ---------------------------------------------------------------------------
__global__ __launch_bounds__(64) void attn(
    const _Float16* __restrict__ qkv,        // [3,500,512,64] f16
    const float* __restrict__ w_o,           // [64,64] f32
    const float* __restrict__ b_o,           // [64] f32
    float* __restrict__ out)                 // [500,16,32,64] f32
{
  __shared__ __align__(16) _Float16 Qs[32*72];
  __shared__ __align__(16) _Float16 Ks[32*72];
  __shared__ __align__(16) _Float16 Vt[64*40];
  __shared__ __align__(16) _Float16 Wm[32*40];
  __shared__ __align__(16) _Float16 wols[64*72];
  __shared__ float bo[64];

  const int lane = threadIdx.x;
  const int t = blockIdx.x >> 4;
  const int b = blockIdx.x & 15;
  const size_t base    = ((size_t)t*NB + b*32)*64;
  const size_t gstride = (size_t)TSTEPS*NB*64;

  #pragma unroll
  for (int it=0; it<4; ++it){
    int idx = it*64 + lane;
    int f = idx >> 3, ko = (idx & 7)*8;
    *(f16x8*)&Qs[f*72+ko] = *(const f16x8*)&qkv[base + (size_t)f*64 + ko];
    *(f16x8*)&Ks[f*72+ko] = *(const f16x8*)&qkv[gstride + base + (size_t)f*64 + ko];
  }
  #pragma unroll
  for (int it=0; it<32; ++it){
    int idx = it*64 + lane;
    int f = idx >> 6, hh = idx & 63;
    Vt[hh*40 + f] = qkv[2*gstride + base + (size_t)f*64 + hh];
  }
  #pragma unroll
  for (int it=0; it<32; ++it){
    int idx = it*64 + lane;
    int c = idx >> 5, hp = (idx & 31)*2;
    float2 u = *(const float2*)(w_o + c*64 + hp);
    wols[c*72 + hp]     = (_Float16)u.x;
    wols[c*72 + hp + 1] = (_Float16)u.y;
  }
  bo[lane] = b_o[lane];

  const int m  = lane & 31;
  const int hk = (lane >> 5) * 8;
  const int rbase = (lane >> 5) * 4;

  // ---- W = Q @ K^T ----
  f32x16 accW;
  #pragma unroll
  for (int i=0;i<16;++i) accW[i]=0.f;
  #pragma unroll
  for (int kb=0; kb<4; ++kb){
    f16x8 a  = *(const f16x8*)&Qs[m*72 + kb*16 + hk];
    f16x8 bb = *(const f16x8*)&Ks[m*72 + kb*16 + hk];
    accW = __builtin_amdgcn_mfma_f32_32x32x16_f16(a, bb, accW, 0, 0, 0);
  }
  #pragma unroll
  for (int r=0; r<16; ++r){
    int row = (r&3) + 8*(r>>2) + rbase;
    Wm[row*40 + m] = (_Float16)accW[r];
  }

  // ---- A = W @ V ----
  f32x16 accA0, accA1;
  #pragma unroll
  for (int i=0;i<16;++i){ accA0[i]=0.f; accA1[i]=0.f; }
  #pragma unroll
  for (int kb=0; kb<2; ++kb){
    f16x8 a  = *(const f16x8*)&Wm[m*40 + kb*16 + hk];
    f16x8 b0 = *(const f16x8*)&Vt[(     m)*40 + kb*16 + hk];
    f16x8 b1 = *(const f16x8*)&Vt[(32 + m)*40 + kb*16 + hk];
    accA0 = __builtin_amdgcn_mfma_f32_32x32x16_f16(a, b0, accA0, 0, 0, 0);
    accA1 = __builtin_amdgcn_mfma_f32_32x32x16_f16(a, b1, accA1, 0, 0, 0);
  }

  // ---- softmax over f ----
  float mx0 = accA0[0], mx1 = accA1[0];
  #pragma unroll
  for (int r=1;r<16;++r){ mx0 = fmaxf(mx0, accA0[r]); mx1 = fmaxf(mx1, accA1[r]); }
  mx0 = fmaxf(mx0, __shfl_xor(mx0, 32, 64));
  mx1 = fmaxf(mx1, __shfl_xor(mx1, 32, 64));
  float s0 = 0.f, s1 = 0.f;
  #pragma unroll
  for (int r=0;r<16;++r){
    float e0 = __builtin_amdgcn_exp2f(LOG2E*(accA0[r]-mx0)); accA0[r]=e0; s0+=e0;
    float e1 = __builtin_amdgcn_exp2f(LOG2E*(accA1[r]-mx1)); accA1[r]=e1; s1+=e1;
  }
  s0 += __shfl_xor(s0, 32, 64);
  s1 += __shfl_xor(s1, 32, 64);
  float i0 = __builtin_amdgcn_rcpf(s0), i1 = __builtin_amdgcn_rcpf(s1);
  #pragma unroll
  for (int r=0;r<16;++r){
    int row = (r&3) + 8*(r>>2) + rbase;
    Qs[row*72 + m]      = (_Float16)(accA0[r]*i0);
    Qs[row*72 + 32 + m] = (_Float16)(accA1[r]*i1);
  }

  // ---- O = P @ w_o^T + b_o ----
  f32x16 accO0, accO1;
  #pragma unroll
  for (int i=0;i<16;++i){ accO0[i]=0.f; accO1[i]=0.f; }
  #pragma unroll
  for (int kb=0; kb<4; ++kb){
    f16x8 a  = *(const f16x8*)&Qs[m*72 + kb*16 + hk];
    f16x8 b0 = *(const f16x8*)&wols[(     m)*72 + kb*16 + hk];
    f16x8 b1 = *(const f16x8*)&wols[(32 + m)*72 + kb*16 + hk];
    accO0 = __builtin_amdgcn_mfma_f32_32x32x16_f16(a, b0, accO0, 0, 0, 0);
    accO1 = __builtin_amdgcn_mfma_f32_32x32x16_f16(a, b1, accO1, 0, 0, 0);
  }
  const size_t obase = ((size_t)t*16 + b)*2048;
  #pragma unroll
  for (int r=0;r<16;++r){
    int row = (r&3) + 8*(r>>2) + rbase;
    out[obase + row*64 + m]      = accO0[r] + bo[m];
    out[obase + row*64 + 32 + m] = accO1[r] + bo[32+m];
  }
}

// ---------------------------------------------------------------------------
extern "C" void kernel_launch(void* const* d_in, const int* in_sizes, int n_in,
                              void* d_out, int out_size, void* d_ws, size_t ws_size,
                              hipStream_t stream)
{
  const float* x  = (const float*)d_in[0];
  const float* st = (const float*)d_in[1];
  _Float16* qkv = (_Float16*)d_ws;   // 98,304,000 B (fits)
  float* out = (float*)d_out;
  float* out_state = out + (size_t)16384000;

  gru_f64<<<dim3(1536), dim3(256), 0, stream>>>(
    x, st,
    (const float*)d_in[2],  (const float*)d_in[3],
    (const float*)d_in[4],  (const float*)d_in[5],
    (const float*)d_in[6],  (const float*)d_in[7],
    (const float*)d_in[8],  (const float*)d_in[9],
    (const float*)d_in[10], (const float*)d_in[11],
    (const float*)d_in[12], (const float*)d_in[13],
    qkv, out_state);

  attn<<<dim3(8000), dim3(64), 0, stream>>>(
    qkv, (const float*)d_in[14], (const float*)d_in[15], out);
}

// Round 5
// 2179.993 us; speedup vs baseline: 5.7685x; 1.0333x over previous
//
#include <hip/hip_runtime.h>

typedef _Float16 f16x8  __attribute__((ext_vector_type(8)));
typedef float    f32x16 __attribute__((ext_vector_type(16)));

#define TSTEPS 500
#define NB 512
#define LOG2E 1.442695041f

// f64 exp, Cody-Waite reduction + degree-11 Taylor, rel err ~1e-15.
__device__ __forceinline__ double exp_d(double v){
  v = fmin(fmax(v, -700.0), 700.0);
  double t = v * 1.4426950408889634;           // v / ln2
  double n = rint(t);
  double f = fma(-n, 6.931471803691238e-01, v);   // LN2_HI
  f = fma(-n, 1.9082149292705877e-10, f);         // LN2_LO
  double p = 2.5052108385441718e-08;           // 1/11!
  p = fma(p, f, 2.7557319223985893e-07);       // 1/10!
  p = fma(p, f, 2.7557319223985888e-06);       // 1/9!
  p = fma(p, f, 2.4801587301587302e-05);       // 1/8!
  p = fma(p, f, 1.9841269841269841e-04);       // 1/7!
  p = fma(p, f, 1.3888888888888889e-03);       // 1/6!
  p = fma(p, f, 8.3333333333333332e-03);       // 1/5!
  p = fma(p, f, 4.1666666666666664e-02);       // 1/4!
  p = fma(p, f, 1.6666666666666666e-01);       // 1/3!
  p = fma(p, f, 0.5);
  p = fma(p, f, 1.0);
  p = fma(p, f, 1.0);
  long long bits = (1023LL + (long long)n) << 52;
  return p * __longlong_as_double(bits);
}

// ---------------------------------------------------------------------------
// Fused GRU, 256 threads (4 waves) per (g,n) sequence.
// Column-split: thread (j=tid>>2, q=tid&3) owns rows {j,64+j,128+j} of W_ih
// and W_hh over cols [16q,16q+16). Weights converted to f64 once (compiler
// may rematerialize to f32+cvt under register pressure — either is fine).
//
// R5 changes:
// (1) __launch_bounds__(256) with NO 2nd arg. Empirical law on this stack:
//     2nd arg w => VGPR cap 256/w AND waves/SIMD capped at w. (256,2) was
//     double-throttling: 128-reg cap (forced cvt remat, killed R4's f64
//     weights) and 2-waves/SIMD ceiling (3 sequential grid rounds at
//     22% occupancy). No 2nd arg: workgroup-fit cap only.
// (2) r/z gate exp packed across lane parity: even-q lanes exp the r
//     pre-activation, odd-q lanes the z one; one 1/(1+e); shfl_xor(.,1)
//     distributes. Bitwise-identical values, 2 exp_d + 2 div per step
//     instead of 3 + 3.
// TRIPWIRE: FETCH_SIZE > 0.5 GB means spills -> revert to (256,2).
// ---------------------------------------------------------------------------
__global__ __launch_bounds__(256) void gru_f64(
    const float* __restrict__ x,    // [500,512,64] f32
    const float* __restrict__ st,   // [3,512,64] f32
    const float* __restrict__ wih0, const float* __restrict__ whh0,
    const float* __restrict__ bih0, const float* __restrict__ bhh0,
    const float* __restrict__ wih1, const float* __restrict__ whh1,
    const float* __restrict__ bih1, const float* __restrict__ bhh1,
    const float* __restrict__ wih2, const float* __restrict__ whh2,
    const float* __restrict__ bih2, const float* __restrict__ bhh2,
    _Float16* __restrict__ qkv,      // ws: [3,500,512,64] f16
    float* __restrict__ out_state)   // [3,512,64] f32
{
  __shared__ __align__(16) double hsh[2][72];
  __shared__ __align__(16) double xsh[2][72];

  const int tid = threadIdx.x;
  const int j = tid >> 2;            // h-index 0..63
  const int q = tid & 3;             // column quarter
  const int g = blockIdx.x >> 9;
  const int n = blockIdx.x & 511;

  const float* wih = (g==0) ? wih0 : ((g==1) ? wih1 : wih2);
  const float* whh = (g==0) ? whh0 : ((g==1) ? whh1 : whh2);
  const float* bih = (g==0) ? bih0 : ((g==1) ? bih1 : bih2);
  const float* bhh = (g==0) ? bhh0 : ((g==1) ? bhh1 : bhh2);

  // f64 weights (converted once): rows j(r), 64+j(z), 128+j(n);
  // cols [16q,16q+16). Loads are float4, perfectly coalesced per lane.
  double wiR[16], wiZ[16], wiN[16], whR[16], whZ[16], whN[16];
  {
    const float4* pR = (const float4*)(wih + (size_t)(       j)*64 + q*16);
    const float4* pZ = (const float4*)(wih + (size_t)( 64 + j)*64 + q*16);
    const float4* pN = (const float4*)(wih + (size_t)(128 + j)*64 + q*16);
    const float4* rR = (const float4*)(whh + (size_t)(       j)*64 + q*16);
    const float4* rZ = (const float4*)(whh + (size_t)( 64 + j)*64 + q*16);
    const float4* rN = (const float4*)(whh + (size_t)(128 + j)*64 + q*16);
    #pragma unroll
    for (int k=0;k<4;++k){
      float4 a;
      a = pR[k]; wiR[4*k]=(double)a.x; wiR[4*k+1]=(double)a.y; wiR[4*k+2]=(double)a.z; wiR[4*k+3]=(double)a.w;
      a = pZ[k]; wiZ[4*k]=(double)a.x; wiZ[4*k+1]=(double)a.y; wiZ[4*k+2]=(double)a.z; wiZ[4*k+3]=(double)a.w;
      a = pN[k]; wiN[4*k]=(double)a.x; wiN[4*k+1]=(double)a.y; wiN[4*k+2]=(double)a.z; wiN[4*k+3]=(double)a.w;
      a = rR[k]; whR[4*k]=(double)a.x; whR[4*k+1]=(double)a.y; whR[4*k+2]=(double)a.z; whR[4*k+3]=(double)a.w;
      a = rZ[k]; whZ[4*k]=(double)a.x; whZ[4*k+1]=(double)a.y; whZ[4*k+2]=(double)a.z; whZ[4*k+3]=(double)a.w;
      a = rN[k]; whN[4*k]=(double)a.x; whN[4*k+1]=(double)a.y; whN[4*k+2]=(double)a.z; whN[4*k+3]=(double)a.w;
    }
  }
  // Biases, folded into accumulator init on the q==0 lane only (so the quad
  // reduce sums each bias exactly once). r/z: b_ih+b_hh folded together.
  const double bRi  = (q==0) ? ((double)bih[j]    + (double)bhh[j]   ) : 0.0;
  const double bZi  = (q==0) ? ((double)bih[64+j] + (double)bhh[64+j]) : 0.0;
  const double biNi = (q==0) ? (double)bih[128+j] : 0.0;
  const double bhNi = (q==0) ? (double)bhh[128+j] : 0.0;

  double h = (double)st[(size_t)(g*512 + n)*64 + j];   // redundant across q

  const float* xp = x + (size_t)n*64 + tid;            // loader lanes tid<64
  float xc0 = 0.f, xc1 = 0.f;
  if (tid < 64){
    int ci = tid + 2*(tid>>4);
    hsh[0][ci] = (double)st[(size_t)(g*512 + n)*64 + tid];
    xsh[0][ci] = (double)xp[0];
    xc0 = xp[(size_t)NB*64];
    xc1 = xp[(size_t)2*NB*64];
  }
  _Float16* qout = qkv + ((size_t)g*TSTEPS*NB + n)*64 + j;
  __syncthreads();

  for (int t=0; t<TSTEPS; ++t){
    const int cur = t & 1, nxt = cur ^ 1;
    const double2* hp = (const double2*)(&hsh[cur][18*q]);  // 144B-aligned
    const double2* xq = (const double2*)(&xsh[cur][18*q]);

    double hdR=bRi, hdZ=bZi, hdN=bhNi, xdR=0.0, xdZ=0.0, xdN=biNi;
    #pragma unroll
    for (int w=0; w<4; ++w){
      double2 h01 = hp[2*w], h23 = hp[2*w+1];
      double2 x01 = xq[2*w], x23 = xq[2*w+1];
      hdR = fma(whR[4*w+0], h01.x, hdR); hdR = fma(whR[4*w+1], h01.y, hdR);
      hdR = fma(whR[4*w+2], h23.x, hdR); hdR = fma(whR[4*w+3], h23.y, hdR);
      hdZ = fma(whZ[4*w+0], h01.x, hdZ); hdZ = fma(whZ[4*w+1], h01.y, hdZ);
      hdZ = fma(whZ[4*w+2], h23.x, hdZ); hdZ = fma(whZ[4*w+3], h23.y, hdZ);
      hdN = fma(whN[4*w+0], h01.x, hdN); hdN = fma(whN[4*w+1], h01.y, hdN);
      hdN = fma(whN[4*w+2], h23.x, hdN); hdN = fma(whN[4*w+3], h23.y, hdN);
      xdR = fma(wiR[4*w+0], x01.x, xdR); xdR = fma(wiR[4*w+1], x01.y, xdR);
      xdR = fma(wiR[4*w+2], x23.x, xdR); xdR = fma(wiR[4*w+3], x23.y, xdR);
      xdZ = fma(wiZ[4*w+0], x01.x, xdZ); xdZ = fma(wiZ[4*w+1], x01.y, xdZ);
      xdZ = fma(wiZ[4*w+2], x23.x, xdZ); xdZ = fma(wiZ[4*w+3], x23.y, xdZ);
      xdN = fma(wiN[4*w+0], x01.x, xdN); xdN = fma(wiN[4*w+1], x01.y, xdN);
      xdN = fma(wiN[4*w+2], x23.x, xdN); xdN = fma(wiN[4*w+3], x23.y, xdN);
    }
    // quad reduce over q (lanes xor 1, 2) — all 4 lanes get identical sums
    hdR += __shfl_xor(hdR, 1, 64); hdR += __shfl_xor(hdR, 2, 64);
    hdZ += __shfl_xor(hdZ, 1, 64); hdZ += __shfl_xor(hdZ, 2, 64);
    hdN += __shfl_xor(hdN, 1, 64); hdN += __shfl_xor(hdN, 2, 64);
    xdR += __shfl_xor(xdR, 1, 64); xdR += __shfl_xor(xdR, 2, 64);
    xdZ += __shfl_xor(xdZ, 1, 64); xdZ += __shfl_xor(xdZ, 2, 64);
    xdN += __shfl_xor(xdN, 1, 64); xdN += __shfl_xor(xdN, 2, 64);

    // r/z gates packed across lane parity: even-q lanes exp the r input,
    // odd-q lanes the z input; shfl_xor(.,1) swaps within the (0,1)/(2,3)
    // pairs. Values bitwise-identical to computing both on every lane.
    double uin = (q & 1) ? -(xdZ + hdZ) : -(xdR + hdR);
    double u   = 1.0/(1.0 + exp_d(uin));
    double up  = __shfl_xor(u, 1, 64);
    double r   = (q & 1) ? up : u;
    double z   = (q & 1) ? u  : up;

    double yn = xdN + r*hdN;                   // biases already inside sums
    double nn = 1.0 - 2.0/(exp_d(2.0*yn) + 1.0);
    h = (1.0 - z)*nn + z*h;

    if (q == 0){
      hsh[nxt][j + 2*(j>>4)] = h;
      qout[(size_t)t*NB*64] = (_Float16)(float)h;   // one-shot rounding
    }
    if (tid < 64){
      xsh[nxt][tid + 2*(tid>>4)] = (double)xc0;     // x[t+1]
      int tp = (t+3 < TSTEPS) ? (t+3) : (TSTEPS-1);
      float xnx = xp[(size_t)tp*NB*64];
      xc0 = xc1; xc1 = xnx;
    }
    __syncthreads();
  }

  if (q == 0)
    out_state[(size_t)(g*512 + n)*64 + j] = (float)h;
}

// ---------------------------------------------------------------------------
// Attention + output projection (unchanged — output 0 passed with it).
// One wave per (t,b) tile; mfma_f32_32x32x16_f16; f32 output.
// ---------------------------------------------------------------------------
__global__ __launch_bounds__(64) void attn(
    const _Float16* __restrict__ qkv,        // [3,500,512,64] f16
    const float* __restrict__ w_o,           // [64,64] f32
    const float* __restrict__ b_o,           // [64] f32
    float* __restrict__ out)                 // [500,16,32,64] f32
{
  __shared__ __align__(16) _Float16 Qs[32*72];
  __shared__ __align__(16) _Float16 Ks[32*72];
  __shared__ __align__(16) _Float16 Vt[64*40];
  __shared__ __align__(16) _Float16 Wm[32*40];
  __shared__ __align__(16) _Float16 wols[64*72];
  __shared__ float bo[64];

  const int lane = threadIdx.x;
  const int t = blockIdx.x >> 4;
  const int b = blockIdx.x & 15;
  const size_t base    = ((size_t)t*NB + b*32)*64;
  const size_t gstride = (size_t)TSTEPS*NB*64;

  #pragma unroll
  for (int it=0; it<4; ++it){
    int idx = it*64 + lane;
    int f = idx >> 3, ko = (idx & 7)*8;
    *(f16x8*)&Qs[f*72+ko] = *(const f16x8*)&qkv[base + (size_t)f*64 + ko];
    *(f16x8*)&Ks[f*72+ko] = *(const f16x8*)&qkv[gstride + base + (size_t)f*64 + ko];
  }
  #pragma unroll
  for (int it=0; it<32; ++it){
    int idx = it*64 + lane;
    int f = idx >> 6, hh = idx & 63;
    Vt[hh*40 + f] = qkv[2*gstride + base + (size_t)f*64 + hh];
  }
  #pragma unroll
  for (int it=0; it<32; ++it){
    int idx = it*64 + lane;
    int c = idx >> 5, hp = (idx & 31)*2;
    float2 u = *(const float2*)(w_o + c*64 + hp);
    wols[c*72 + hp]     = (_Float16)u.x;
    wols[c*72 + hp + 1] = (_Float16)u.y;
  }
  bo[lane] = b_o[lane];

  const int m  = lane & 31;
  const int hk = (lane >> 5) * 8;
  const int rbase = (lane >> 5) * 4;

  // ---- W = Q @ K^T ----
  f32x16 accW;
  #pragma unroll
  for (int i=0;i<16;++i) accW[i]=0.f;
  #pragma unroll
  for (int kb=0; kb<4; ++kb){
    f16x8 a  = *(const f16x8*)&Qs[m*72 + kb*16 + hk];
    f16x8 bb = *(const f16x8*)&Ks[m*72 + kb*16 + hk];
    accW = __builtin_amdgcn_mfma_f32_32x32x16_f16(a, bb, accW, 0, 0, 0);
  }
  #pragma unroll
  for (int r=0; r<16; ++r){
    int row = (r&3) + 8*(r>>2) + rbase;
    Wm[row*40 + m] = (_Float16)accW[r];
  }

  // ---- A = W @ V ----
  f32x16 accA0, accA1;
  #pragma unroll
  for (int i=0;i<16;++i){ accA0[i]=0.f; accA1[i]=0.f; }
  #pragma unroll
  for (int kb=0; kb<2; ++kb){
    f16x8 a  = *(const f16x8*)&Wm[m*40 + kb*16 + hk];
    f16x8 b0 = *(const f16x8*)&Vt[(     m)*40 + kb*16 + hk];
    f16x8 b1 = *(const f16x8*)&Vt[(32 + m)*40 + kb*16 + hk];
    accA0 = __builtin_amdgcn_mfma_f32_32x32x16_f16(a, b0, accA0, 0, 0, 0);
    accA1 = __builtin_amdgcn_mfma_f32_32x32x16_f16(a, b1, accA1, 0, 0, 0);
  }

  // ---- softmax over f ----
  float mx0 = accA0[0], mx1 = accA1[0];
  #pragma unroll
  for (int r=1;r<16;++r){ mx0 = fmaxf(mx0, accA0[r]); mx1 = fmaxf(mx1, accA1[r]); }
  mx0 = fmaxf(mx0, __shfl_xor(mx0, 32, 64));
  mx1 = fmaxf(mx1, __shfl_xor(mx1, 32, 64));
  float s0 = 0.f, s1 = 0.f;
  #pragma unroll
  for (int r=0;r<16;++r){
    float e0 = __builtin_amdgcn_exp2f(LOG2E*(accA0[r]-mx0)); accA0[r]=e0; s0+=e0;
    float e1 = __builtin_amdgcn_exp2f(LOG2E*(accA1[r]-mx1)); accA1[r]=e1; s1+=e1;
  }
  s0 += __shfl_xor(s0, 32, 64);
  s1 += __shfl_xor(s1, 32, 64);
  float i0 = __builtin_amdgcn_rcpf(s0), i1 = __builtin_amdgcn_rcpf(s1);
  #pragma unroll
  for (int r=0;r<16;++r){
    int row = (r&3) + 8*(r>>2) + rbase;
    Qs[row*72 + m]      = (_Float16)(accA0[r]*i0);
    Qs[row*72 + 32 + m] = (_Float16)(accA1[r]*i1);
  }

  // ---- O = P @ w_o^T + b_o ----
  f32x16 accO0, accO1;
  #pragma unroll
  for (int i=0;i<16;++i){ accO0[i]=0.f; accO1[i]=0.f; }
  #pragma unroll
  for (int kb=0; kb<4; ++kb){
    f16x8 a  = *(const f16x8*)&Qs[m*72 + kb*16 + hk];
    f16x8 b0 = *(const f16x8*)&wols[(     m)*72 + kb*16 + hk];
    f16x8 b1 = *(const f16x8*)&wols[(32 + m)*72 + kb*16 + hk];
    accO0 = __builtin_amdgcn_mfma_f32_32x32x16_f16(a, b0, accO0, 0, 0, 0);
    accO1 = __builtin_amdgcn_mfma_f32_32x32x16_f16(a, b1, accO1, 0, 0, 0);
  }
  const size_t obase = ((size_t)t*16 + b)*2048;
  #pragma unroll
  for (int r=0;r<16;++r){
    int row = (r&3) + 8*(r>>2) + rbase;
    out[obase + row*64 + m]      = accO0[r] + bo[m];
    out[obase + row*64 + 32 + m] = accO1[r] + bo[32+m];
  }
}

// ---------------------------------------------------------------------------
extern "C" void kernel_launch(void* const* d_in, const int* in_sizes, int n_in,
                              void* d_out, int out_size, void* d_ws, size_t ws_size,
                              hipStream_t stream)
{
  const float* x  = (const float*)d_in[0];
  const float* st = (const float*)d_in[1];
  _Float16* qkv = (_Float16*)d_ws;   // 98,304,000 B (fits)
  float* out = (float*)d_out;
  float* out_state = out + (size_t)16384000;

  gru_f64<<<dim3(1536), dim3(256), 0, stream>>>(
    x, st,
    (const float*)d_in[2],  (const float*)d_in[3],
    (const float*)d_in[4],  (const float*)d_in[5],
    (const float*)d_in[6],  (const float*)d_in[7],
    (const float*)d_in[8],  (const float*)d_in[9],
    (const float*)d_in[10], (const float*)d_in[11],
    (const float*)d_in[12], (const float*)d_in[13],
    qkv, out_state);

  attn<<<dim3(8000), dim3(64), 0, stream>>>(
    qkv, (const float*)d_in[14], (const float*)d_in[15], out);
}

// Round 6
// 2177.151 us; speedup vs baseline: 5.7760x; 1.0013x over previous
//
#include <hip/hip_runtime.h>

typedef _Float16 f16x8  __attribute__((ext_vector_type(8)));
typedef float    f32x16 __attribute__((ext_vector_type(16)));

#define TSTEPS 500
#define NB 512
#define LOG2E 1.442695041f

// f64 exp, Cody-Waite reduction + degree-11 Taylor, rel err ~1e-15.
__device__ __forceinline__ double exp_d(double v){
  v = fmin(fmax(v, -700.0), 700.0);
  double t = v * 1.4426950408889634;           // v / ln2
  double n = rint(t);
  double f = fma(-n, 6.931471803691238e-01, v);   // LN2_HI
  f = fma(-n, 1.9082149292705877e-10, f);         // LN2_LO
  double p = 2.5052108385441718e-08;           // 1/11!
  p = fma(p, f, 2.7557319223985893e-07);       // 1/10!
  p = fma(p, f, 2.7557319223985888e-06);       // 1/9!
  p = fma(p, f, 2.4801587301587302e-05);       // 1/8!
  p = fma(p, f, 1.9841269841269841e-04);       // 1/7!
  p = fma(p, f, 1.3888888888888889e-03);       // 1/6!
  p = fma(p, f, 8.3333333333333332e-03);       // 1/5!
  p = fma(p, f, 4.1666666666666664e-02);       // 1/4!
  p = fma(p, f, 1.6666666666666666e-01);       // 1/3!
  p = fma(p, f, 0.5);
  p = fma(p, f, 1.0);
  p = fma(p, f, 1.0);
  long long bits = (1023LL + (long long)n) << 52;
  return p * __longlong_as_double(bits);
}

// 1/x via v_rcp_f64 + 2 Newton steps. ~1e-16 rel err (vs IEEE div's 0.5ulp)
// at roughly half the instruction count. Per-step perturbation ~1e-16
// amplified 4e5x over the recurrence -> ~4e-11, invisible vs the f16 floor.
__device__ __forceinline__ double rcp_nr(double x){
  double r;
  asm("v_rcp_f64 %0, %1" : "=v"(r) : "v"(x));
  r = fma(fma(-x, r, 1.0), r, r);
  r = fma(fma(-x, r, 1.0), r, r);
  return r;
}

// ---------------------------------------------------------------------------
// Fused GRU, 256 threads (4 waves) per (g,n) sequence.
// Dot phase (all waves): thread (j=tid>>2, q=tid&3) owns rows {j,64+j,128+j}
// of W_ih/W_hh over cols [16q,16q+16); quad shfl_xor reduce; q==0 lanes
// publish 4 reduced pre-activations per row to psh.
//
// R6 change — GATE DESPECIALIZATION: gates were issued by all 4 waves
// (4x redundant at wave granularity: an exp_d is ONE wave-instruction
// whether 16 or 64 rows ride in its lanes). Now wave 0 (lane l <-> row l)
// computes all 64 rows' gates ONCE per step (~350 cy instead of 4x~320),
// updates h, writes hsh + qkv (single coalesced 64-lane store). Wave 1's
// lanes stage next-step x concurrently. Two barriers/step; hsh/xsh/psh are
// single-buffered (writes barrier-separated from reads).
// R6 change 2: both f64 divisions -> rcp_nr (v_rcp_f64 + 2NR).
// Keep __launch_bounds__(256,2): VGPR must stay <=128 (129+ would halve
// residency on this stack; compiler remats f64 weights to f32+cvt, known
// good). TRIPWIRE: FETCH >0.5GB = spills -> revert.
// ---------------------------------------------------------------------------
__global__ __launch_bounds__(256, 2) void gru_f64(
    const float* __restrict__ x,    // [500,512,64] f32
    const float* __restrict__ st,   // [3,512,64] f32
    const float* __restrict__ wih0, const float* __restrict__ whh0,
    const float* __restrict__ bih0, const float* __restrict__ bhh0,
    const float* __restrict__ wih1, const float* __restrict__ whh1,
    const float* __restrict__ bih1, const float* __restrict__ bhh1,
    const float* __restrict__ wih2, const float* __restrict__ whh2,
    const float* __restrict__ bih2, const float* __restrict__ bhh2,
    _Float16* __restrict__ qkv,      // ws: [3,500,512,64] f16
    float* __restrict__ out_state)   // [3,512,64] f32
{
  __shared__ __align__(16) double hsh[72];
  __shared__ __align__(16) double xsh[72];
  __shared__ __align__(16) double psh[4][72];   // r-pre, z-pre, xn, hn per row

  const int tid = threadIdx.x;
  const int j = tid >> 2;            // h-row 0..63 (dot phase)
  const int q = tid & 3;             // column quarter (dot phase)
  const int g = blockIdx.x >> 9;
  const int n = blockIdx.x & 511;

  const float* wih = (g==0) ? wih0 : ((g==1) ? wih1 : wih2);
  const float* whh = (g==0) ? whh0 : ((g==1) ? whh1 : whh2);
  const float* bih = (g==0) ? bih0 : ((g==1) ? bih1 : bih2);
  const float* bhh = (g==0) ? bhh0 : ((g==1) ? bhh1 : bhh2);

  // Weights: rows j(r), 64+j(z), 128+j(n); cols [16q,16q+16). f64 arrays;
  // the allocator remats to f32+cvt under the 128-reg cap (known good).
  double wiR[16], wiZ[16], wiN[16], whR[16], whZ[16], whN[16];
  {
    const float4* pR = (const float4*)(wih + (size_t)(       j)*64 + q*16);
    const float4* pZ = (const float4*)(wih + (size_t)( 64 + j)*64 + q*16);
    const float4* pN = (const float4*)(wih + (size_t)(128 + j)*64 + q*16);
    const float4* rR = (const float4*)(whh + (size_t)(       j)*64 + q*16);
    const float4* rZ = (const float4*)(whh + (size_t)( 64 + j)*64 + q*16);
    const float4* rN = (const float4*)(whh + (size_t)(128 + j)*64 + q*16);
    #pragma unroll
    for (int k=0;k<4;++k){
      float4 a;
      a = pR[k]; wiR[4*k]=(double)a.x; wiR[4*k+1]=(double)a.y; wiR[4*k+2]=(double)a.z; wiR[4*k+3]=(double)a.w;
      a = pZ[k]; wiZ[4*k]=(double)a.x; wiZ[4*k+1]=(double)a.y; wiZ[4*k+2]=(double)a.z; wiZ[4*k+3]=(double)a.w;
      a = pN[k]; wiN[4*k]=(double)a.x; wiN[4*k+1]=(double)a.y; wiN[4*k+2]=(double)a.z; wiN[4*k+3]=(double)a.w;
      a = rR[k]; whR[4*k]=(double)a.x; whR[4*k+1]=(double)a.y; whR[4*k+2]=(double)a.z; whR[4*k+3]=(double)a.w;
      a = rZ[k]; whZ[4*k]=(double)a.x; whZ[4*k+1]=(double)a.y; whZ[4*k+2]=(double)a.z; whZ[4*k+3]=(double)a.w;
      a = rN[k]; whN[4*k]=(double)a.x; whN[4*k+1]=(double)a.y; whN[4*k+2]=(double)a.z; whN[4*k+3]=(double)a.w;
    }
  }
  // Biases folded into accumulator init on q==0 lanes (butterfly reduce sums
  // each bias exactly once). r/z: b_ih+b_hh folded together.
  const double bRi  = (q==0) ? ((double)bih[j]    + (double)bhh[j]   ) : 0.0;
  const double bZi  = (q==0) ? ((double)bih[64+j] + (double)bhh[64+j]) : 0.0;
  const double biNi = (q==0) ? (double)bih[128+j] : 0.0;
  const double bhNi = (q==0) ? (double)bhh[128+j] : 0.0;

  const int l2 = tid & 63;
  const float* xp = x + (size_t)n*64 + l2;

  double h = 0.0;                    // live state: wave 0, lane l <-> row l
  float xc0 = 0.f, xc1 = 0.f;        // x prefetch pipeline: wave 1 lanes
  if (tid < 64){
    h = (double)st[(size_t)(g*512 + n)*64 + tid];
    hsh[tid + 2*(tid>>4)] = h;
  } else if (tid < 128){
    xsh[l2 + 2*(l2>>4)] = (double)xp[0];
    xc0 = xp[(size_t)NB*64];
    xc1 = xp[(size_t)2*NB*64];
  }
  _Float16* qout = qkv + ((size_t)g*TSTEPS*NB + n)*64 + tid;  // used by tid<64
  __syncthreads();

  for (int t=0; t<TSTEPS; ++t){
    // ---- dot phase: all 256 threads ----
    const double2* hp = (const double2*)(&hsh[18*q]);  // 144B-aligned
    const double2* xq = (const double2*)(&xsh[18*q]);

    double hdR=bRi, hdZ=bZi, hdN=bhNi, xdR=0.0, xdZ=0.0, xdN=biNi;
    #pragma unroll
    for (int w=0; w<4; ++w){
      double2 h01 = hp[2*w], h23 = hp[2*w+1];
      double2 x01 = xq[2*w], x23 = xq[2*w+1];
      hdR = fma(whR[4*w+0], h01.x, hdR); hdR = fma(whR[4*w+1], h01.y, hdR);
      hdR = fma(whR[4*w+2], h23.x, hdR); hdR = fma(whR[4*w+3], h23.y, hdR);
      hdZ = fma(whZ[4*w+0], h01.x, hdZ); hdZ = fma(whZ[4*w+1], h01.y, hdZ);
      hdZ = fma(whZ[4*w+2], h23.x, hdZ); hdZ = fma(whZ[4*w+3], h23.y, hdZ);
      hdN = fma(whN[4*w+0], h01.x, hdN); hdN = fma(whN[4*w+1], h01.y, hdN);
      hdN = fma(whN[4*w+2], h23.x, hdN); hdN = fma(whN[4*w+3], h23.y, hdN);
      xdR = fma(wiR[4*w+0], x01.x, xdR); xdR = fma(wiR[4*w+1], x01.y, xdR);
      xdR = fma(wiR[4*w+2], x23.x, xdR); xdR = fma(wiR[4*w+3], x23.y, xdR);
      xdZ = fma(wiZ[4*w+0], x01.x, xdZ); xdZ = fma(wiZ[4*w+1], x01.y, xdZ);
      xdZ = fma(wiZ[4*w+2], x23.x, xdZ); xdZ = fma(wiZ[4*w+3], x23.y, xdZ);
      xdN = fma(wiN[4*w+0], x01.x, xdN); xdN = fma(wiN[4*w+1], x01.y, xdN);
      xdN = fma(wiN[4*w+2], x23.x, xdN); xdN = fma(wiN[4*w+3], x23.y, xdN);
    }
    // quad reduce over q (lanes xor 1, 2) — all 4 lanes get identical sums
    hdR += __shfl_xor(hdR, 1, 64); hdR += __shfl_xor(hdR, 2, 64);
    hdZ += __shfl_xor(hdZ, 1, 64); hdZ += __shfl_xor(hdZ, 2, 64);
    hdN += __shfl_xor(hdN, 1, 64); hdN += __shfl_xor(hdN, 2, 64);
    xdR += __shfl_xor(xdR, 1, 64); xdR += __shfl_xor(xdR, 2, 64);
    xdZ += __shfl_xor(xdZ, 1, 64); xdZ += __shfl_xor(xdZ, 2, 64);
    xdN += __shfl_xor(xdN, 1, 64); xdN += __shfl_xor(xdN, 2, 64);

    if (q == 0){
      psh[0][j] = hdR + xdR;     // r pre-activation (biases already inside)
      psh[1][j] = hdZ + xdZ;     // z pre-activation
      psh[2][j] = xdN;           // x-side n (incl b_ih_n)
      psh[3][j] = hdN;           // h-side n (incl b_hh_n)
    }
    __syncthreads();             // b1: pre-activations published

    // ---- gate phase: wave 0 only (lane l <-> row l), issued ONCE ----
    if (tid < 64){
      double aR = psh[0][tid];
      double aZ = psh[1][tid];
      double xn = psh[2][tid];
      double hn = psh[3][tid];
      double r  = rcp_nr(1.0 + exp_d(-aR));
      double z  = rcp_nr(1.0 + exp_d(-aZ));
      double yn = xn + r*hn;
      double nn = 1.0 - 2.0*rcp_nr(exp_d(2.0*yn) + 1.0);
      h = (1.0 - z)*nn + z*h;
      hsh[tid + 2*(tid>>4)] = h;
      qout[(size_t)t*NB*64] = (_Float16)(float)h;   // one-shot rounding
    } else if (tid < 128){
      // wave 1: stage x[t+1] (overlaps wave 0's gate chain)
      xsh[l2 + 2*(l2>>4)] = (double)xc0;
      int tp = (t+3 < TSTEPS) ? (t+3) : (TSTEPS-1);
      float xnx = xp[(size_t)tp*NB*64];
      xc0 = xc1; xc1 = xnx;
    }
    __syncthreads();             // b2: h[t+1], x[t+1] visible
  }

  if (tid < 64)
    out_state[(size_t)(g*512 + n)*64 + tid] = (float)h;
}

// ---------------------------------------------------------------------------
// Attention + output projection (unchanged — output 0 passed with it).
// One wave per (t,b) tile; mfma_f32_32x32x16_f16; f32 output.
// ---------------------------------------------------------------------------
__global__ __launch_bounds__(64) void attn(
    const _Float16* __restrict__ qkv,        // [3,500,512,64] f16
    const float* __restrict__ w_o,           // [64,64] f32
    const float* __restrict__ b_o,           // [64] f32
    float* __restrict__ out)                 // [500,16,32,64] f32
{
  __shared__ __align__(16) _Float16 Qs[32*72];
  __shared__ __align__(16) _Float16 Ks[32*72];
  __shared__ __align__(16) _Float16 Vt[64*40];
  __shared__ __align__(16) _Float16 Wm[32*40];
  __shared__ __align__(16) _Float16 wols[64*72];
  __shared__ float bo[64];

  const int lane = threadIdx.x;
  const int t = blockIdx.x >> 4;
  const int b = blockIdx.x & 15;
  const size_t base    = ((size_t)t*NB + b*32)*64;
  const size_t gstride = (size_t)TSTEPS*NB*64;

  #pragma unroll
  for (int it=0; it<4; ++it){
    int idx = it*64 + lane;
    int f = idx >> 3, ko = (idx & 7)*8;
    *(f16x8*)&Qs[f*72+ko] = *(const f16x8*)&qkv[base + (size_t)f*64 + ko];
    *(f16x8*)&Ks[f*72+ko] = *(const f16x8*)&qkv[gstride + base + (size_t)f*64 + ko];
  }
  #pragma unroll
  for (int it=0; it<32; ++it){
    int idx = it*64 + lane;
    int f = idx >> 6, hh = idx & 63;
    Vt[hh*40 + f] = qkv[2*gstride + base + (size_t)f*64 + hh];
  }
  #pragma unroll
  for (int it=0; it<32; ++it){
    int idx = it*64 + lane;
    int c = idx >> 5, hp = (idx & 31)*2;
    float2 u = *(const float2*)(w_o + c*64 + hp);
    wols[c*72 + hp]     = (_Float16)u.x;
    wols[c*72 + hp + 1] = (_Float16)u.y;
  }
  bo[lane] = b_o[lane];

  const int m  = lane & 31;
  const int hk = (lane >> 5) * 8;
  const int rbase = (lane >> 5) * 4;

  // ---- W = Q @ K^T ----
  f32x16 accW;
  #pragma unroll
  for (int i=0;i<16;++i) accW[i]=0.f;
  #pragma unroll
  for (int kb=0; kb<4; ++kb){
    f16x8 a  = *(const f16x8*)&Qs[m*72 + kb*16 + hk];
    f16x8 bb = *(const f16x8*)&Ks[m*72 + kb*16 + hk];
    accW = __builtin_amdgcn_mfma_f32_32x32x16_f16(a, bb, accW, 0, 0, 0);
  }
  #pragma unroll
  for (int r=0; r<16; ++r){
    int row = (r&3) + 8*(r>>2) + rbase;
    Wm[row*40 + m] = (_Float16)accW[r];
  }

  // ---- A = W @ V ----
  f32x16 accA0, accA1;
  #pragma unroll
  for (int i=0;i<16;++i){ accA0[i]=0.f; accA1[i]=0.f; }
  #pragma unroll
  for (int kb=0; kb<2; ++kb){
    f16x8 a  = *(const f16x8*)&Wm[m*40 + kb*16 + hk];
    f16x8 b0 = *(const f16x8*)&Vt[(     m)*40 + kb*16 + hk];
    f16x8 b1 = *(const f16x8*)&Vt[(32 + m)*40 + kb*16 + hk];
    accA0 = __builtin_amdgcn_mfma_f32_32x32x16_f16(a, b0, accA0, 0, 0, 0);
    accA1 = __builtin_amdgcn_mfma_f32_32x32x16_f16(a, b1, accA1, 0, 0, 0);
  }

  // ---- softmax over f ----
  float mx0 = accA0[0], mx1 = accA1[0];
  #pragma unroll
  for (int r=1;r<16;++r){ mx0 = fmaxf(mx0, accA0[r]); mx1 = fmaxf(mx1, accA1[r]); }
  mx0 = fmaxf(mx0, __shfl_xor(mx0, 32, 64));
  mx1 = fmaxf(mx1, __shfl_xor(mx1, 32, 64));
  float s0 = 0.f, s1 = 0.f;
  #pragma unroll
  for (int r=0;r<16;++r){
    float e0 = __builtin_amdgcn_exp2f(LOG2E*(accA0[r]-mx0)); accA0[r]=e0; s0+=e0;
    float e1 = __builtin_amdgcn_exp2f(LOG2E*(accA1[r]-mx1)); accA1[r]=e1; s1+=e1;
  }
  s0 += __shfl_xor(s0, 32, 64);
  s1 += __shfl_xor(s1, 32, 64);
  float i0 = __builtin_amdgcn_rcpf(s0), i1 = __builtin_amdgcn_rcpf(s1);
  #pragma unroll
  for (int r=0;r<16;++r){
    int row = (r&3) + 8*(r>>2) + rbase;
    Qs[row*72 + m]      = (_Float16)(accA0[r]*i0);
    Qs[row*72 + 32 + m] = (_Float16)(accA1[r]*i1);
  }

  // ---- O = P @ w_o^T + b_o ----
  f32x16 accO0, accO1;
  #pragma unroll
  for (int i=0;i<16;++i){ accO0[i]=0.f; accO1[i]=0.f; }
  #pragma unroll
  for (int kb=0; kb<4; ++kb){
    f16x8 a  = *(const f16x8*)&Qs[m*72 + kb*16 + hk];
    f16x8 b0 = *(const f16x8*)&wols[(     m)*72 + kb*16 + hk];
    f16x8 b1 = *(const f16x8*)&wols[(32 + m)*72 + kb*16 + hk];
    accO0 = __builtin_amdgcn_mfma_f32_32x32x16_f16(a, b0, accO0, 0, 0, 0);
    accO1 = __builtin_amdgcn_mfma_f32_32x32x16_f16(a, b1, accO1, 0, 0, 0);
  }
  const size_t obase = ((size_t)t*16 + b)*2048;
  #pragma unroll
  for (int r=0;r<16;++r){
    int row = (r&3) + 8*(r>>2) + rbase;
    out[obase + row*64 + m]      = accO0[r] + bo[m];
    out[obase + row*64 + 32 + m] = accO1[r] + bo[32+m];
  }
}

// ---------------------------------------------------------------------------
extern "C" void kernel_launch(void* const* d_in, const int* in_sizes, int n_in,
                              void* d_out, int out_size, void* d_ws, size_t ws_size,
                              hipStream_t stream)
{
  const float* x  = (const float*)d_in[0];
  const float* st = (const float*)d_in[1];
  _Float16* qkv = (_Float16*)d_ws;   // 98,304,000 B (fits)
  float* out = (float*)d_out;
  float* out_state = out + (size_t)16384000;

  gru_f64<<<dim3(1536), dim3(256), 0, stream>>>(
    x, st,
    (const float*)d_in[2],  (const float*)d_in[3],
    (const float*)d_in[4],  (const float*)d_in[5],
    (const float*)d_in[6],  (const float*)d_in[7],
    (const float*)d_in[8],  (const float*)d_in[9],
    (const float*)d_in[10], (const float*)d_in[11],
    (const float*)d_in[12], (const float*)d_in[13],
    qkv, out_state);

  attn<<<dim3(8000), dim3(64), 0, stream>>>(
    qkv, (const float*)d_in[14], (const float*)d_in[15], out);
}